// Round 2
// baseline (869.509 us; speedup 1.0000x reference)
//
#include <hip/hip_runtime.h>
#include <cstddef>
#include <cstdint>

#define GG 4
#define SS 2048
#define MM 1024
#define EE 64
#define CAP 160            // int(8192/64 * 1.25) = 160 exactly, >= MIN_EXPERT_CAPACITY
#define ROWQ (CAP / 4)     // 40 float4 per (g,s,e) row

// ---------------------------------------------------------------------------
// Kernel A: gating — logits (token x expert dot products), softmax, argmax,
// gate value, and per-(g,e) softmax-mass accumulation (aux-loss proxy).
// Layout: lane = expert (64 lanes == 64 experts), each wave owns 4 tokens,
// 4 waves per block => 16 tokens/block, 512 blocks.
// ---------------------------------------------------------------------------
__global__ __launch_bounds__(256) void gating_kernel(
    const float* __restrict__ x,      // [G*S, M]
    const float* __restrict__ W,      // [M, E]
    int*   __restrict__ expert_out,   // [G*S]
    float* __restrict__ gate_out,     // [G*S]
    float* __restrict__ proxy)        // [G*E], pre-zeroed
{
    __shared__ float lds_proxy[EE];
    const int tid  = threadIdx.x;
    const int wave = tid >> 6;
    const int lane = tid & 63;        // = expert index for this lane

    if (tid < EE) lds_proxy[tid] = 0.0f;
    __syncthreads();

    const int t0 = blockIdx.x * 16 + wave * 4;      // first of 4 tokens
    const float* xr = x + (size_t)t0 * MM;

    float acc[4][4];
#pragma unroll
    for (int i = 0; i < 4; ++i)
#pragma unroll
        for (int j = 0; j < 4; ++j) acc[i][j] = 0.0f;

    for (int m = 0; m < MM; m += 4) {
        const float w0 = W[(m + 0) * EE + lane];
        const float w1 = W[(m + 1) * EE + lane];
        const float w2 = W[(m + 2) * EE + lane];
        const float w3 = W[(m + 3) * EE + lane];
#pragma unroll
        for (int i = 0; i < 4; ++i) {
            const float4 xv = *reinterpret_cast<const float4*>(xr + (size_t)i * MM + m);
            acc[i][0] = fmaf(xv.x, w0, acc[i][0]);
            acc[i][1] = fmaf(xv.y, w1, acc[i][1]);
            acc[i][2] = fmaf(xv.z, w2, acc[i][2]);
            acc[i][3] = fmaf(xv.w, w3, acc[i][3]);
        }
    }

    const int g = blockIdx.x / (SS / 16);   // 16 tokens/block, 2048 tokens/group

#pragma unroll
    for (int i = 0; i < 4; ++i) {
        // combine stripes in fp64 (deterministic, high accuracy for argmax)
        double logit = ((double)acc[i][0] + (double)acc[i][1]) +
                       ((double)acc[i][2] + (double)acc[i][3]);

        // argmax over lanes, first-index tie-break (np.argmax semantics)
        double v = logit;
        int idx = lane;
        for (int off = 32; off; off >>= 1) {
            double ov = __shfl_xor(v, off);
            int    oi = __shfl_xor(idx, off);
            if (ov > v || (ov == v && oi < idx)) { v = ov; idx = oi; }
        }

        // softmax denominator (shifted by max)
        float p  = __expf((float)(logit - v));
        float ps = p;
        for (int off = 32; off; off >>= 1) ps += __shfl_xor(ps, off);
        float inv = 1.0f / ps;            // = softmax value at the argmax

        atomicAdd(&lds_proxy[lane], p * inv);   // this lane's expert prob

        if (lane == 0) {
            expert_out[t0 + i] = idx;
            gate_out[t0 + i]   = inv;
        }
    }

    __syncthreads();
    if (tid < EE) atomicAdd(&proxy[g * EE + tid], lds_proxy[tid]);
}

// ---------------------------------------------------------------------------
// Kernel B: exclusive cumsum over the sequence axis per (g,e) via ballot scan.
// One wave per (g,e) pair: 256 waves -> 64 blocks x 256 threads.
// Every token gets pos[] written (by the wave owning its expert).
// ---------------------------------------------------------------------------
__global__ __launch_bounds__(256) void scan_kernel(
    const int* __restrict__ expert,   // [G*S]
    int* __restrict__ pos,            // [G*S]
    int* __restrict__ count)          // [G*E]
{
    const int wid  = (int)((blockIdx.x * blockDim.x + threadIdx.x) >> 6); // 0..255
    const int lane = threadIdx.x & 63;
    const int g = wid >> 6;
    const int e = wid & 63;
    const int* ex = expert + g * SS;

    int running = 0;
    for (int s0 = 0; s0 < SS; s0 += 64) {
        const int myex = ex[s0 + lane];
        const unsigned long long m = __ballot(myex == e);
        if (myex == e) {
            const int r = __popcll(m & ((1ull << lane) - 1ull));
            pos[g * SS + s0 + lane] = running + r;
        }
        running += __popcll(m);
    }
    if (lane == 0) count[g * EE + e] = running;
}

// ---------------------------------------------------------------------------
// Kernel C: aux load-balancing loss (scalar).
// ---------------------------------------------------------------------------
__global__ __launch_bounds__(256) void aux_kernel(
    const float* __restrict__ proxy,  // [G*E] sum of probs over s
    const int*   __restrict__ count,  // [G*E] token counts
    float* __restrict__ out_aux)
{
    __shared__ float red[4];
    const int i = threadIdx.x;        // 0..255 -> (g,e)
    const float denom = (float)SS * (1.0f + 1e-6f);
    float term = (proxy[i] / denom) * ((float)count[i] / denom);
    for (int off = 32; off; off >>= 1) term += __shfl_xor(term, off);
    if ((i & 63) == 0) red[i >> 6] = term;
    __syncthreads();
    if (i == 0) {
        float tot = (red[0] + red[1]) + (red[2] + red[3]);
        *out_aux = tot / (float)(GG * EE) * ((float)(EE * EE) * 0.01f);
    }
}

// ---------------------------------------------------------------------------
// Kernel D: paint — write the ENTIRE combine_tensor and dispatch_mask in one
// coalesced streaming pass (zeros + the single kept slot per token).
// One block per token: 64 e-rows x 40 float4 = 2560 float4 per tensor,
// 256 threads x 10 iterations, x2 tensors. Exactly 671 MB of HBM writes.
// ---------------------------------------------------------------------------
__global__ __launch_bounds__(256) void paint_kernel(
    const int*   __restrict__ expert,
    const float* __restrict__ gate,
    const int*   __restrict__ pos,
    float4* __restrict__ out)         // combine as float4; dispatch at +N4
{
    const int t   = blockIdx.x;       // token 0..8191
    const int e_t = expert[t];
    const int p   = pos[t];
    const float gv = gate[t];
    const bool kept = (p < CAP);
    const int hot_idx = e_t * ROWQ + (p >> 2);   // float4 index within row-group

    const size_t base = (size_t)t * (EE * ROWQ);
    const size_t N4   = (size_t)GG * SS * (EE * ROWQ);

    const float4 z = make_float4(0.f, 0.f, 0.f, 0.f);
#pragma unroll
    for (int k = 0; k < (EE * ROWQ) / 256; ++k) {
        const int idx = threadIdx.x + k * 256;
        float4 vc = z, vd = z;
        if (kept && idx == hot_idx) {
            reinterpret_cast<float*>(&vc)[p & 3] = gv;
            reinterpret_cast<float*>(&vd)[p & 3] = 1.0f;
        }
        out[base + idx]      = vc;
        out[N4 + base + idx] = vd;
    }
}

// ---------------------------------------------------------------------------
extern "C" void kernel_launch(void* const* d_in, const int* in_sizes, int n_in,
                              void* d_out, int out_size, void* d_ws, size_t ws_size,
                              hipStream_t stream) {
    const float* x = (const float*)d_in[0];
    const float* W = (const float*)d_in[1];
    float* out = (float*)d_out;

    const int tokens = GG * SS;                         // 8192
    const size_t N = (size_t)tokens * EE * CAP;         // G*S*E*C elements

    // workspace layout
    float* proxy  = (float*)d_ws;                // G*E floats (needs zeroing)
    int*   expert = (int*)(proxy + GG * EE);     // G*S ints
    float* gate   = (float*)(expert + tokens);   // G*S floats
    int*   pos    = (int*)(gate + tokens);       // G*S ints
    int*   count  = (int*)(pos + tokens);        // G*E ints

    hipMemsetAsync(proxy, 0, (size_t)(GG * EE) * sizeof(float), stream);

    gating_kernel<<<tokens / 16, 256, 0, stream>>>(x, W, expert, gate, proxy);
    scan_kernel<<<(GG * EE) / 4, 256, 0, stream>>>(expert, pos, count);
    aux_kernel<<<1, 256, 0, stream>>>(proxy, count, out + 2 * N);
    paint_kernel<<<tokens, 256, 0, stream>>>(expert, gate, pos, (float4*)out);
}

// Round 5
// 853.524 us; speedup vs baseline: 1.0187x; 1.0187x over previous
//
#include <hip/hip_runtime.h>
#include <cstddef>
#include <cstdint>

#define GG 4
#define SS 2048
#define MM 1024
#define EE 64
#define CAP 160            // int(8192/64 * 1.25) = 160, >= MIN_EXPERT_CAPACITY
#define ROWQ (CAP / 4)     // 40 float4 per (g,s,e) row
#define TOKENS (GG * SS)   // 8192
#define BLK_PER_G (SS / 16)  // 128 gating blocks per group

typedef float floatx4 __attribute__((ext_vector_type(4)));  // native vector for nontemporal builtins

// ---------------------------------------------------------------------------
// Kernel A: gating — logits, softmax, argmax, gate value, per-block proxy
// partials (no atomics, no pre-zeroing). lane = expert, 4 tokens/wave,
// 16 tokens/block, 512 blocks.
// ---------------------------------------------------------------------------
__global__ __launch_bounds__(256) void gating_kernel(
    const float* __restrict__ x,       // [G*S, M]
    const float* __restrict__ W,       // [M, E]
    int*   __restrict__ expert_out,    // [G*S]
    float* __restrict__ gate_out,      // [G*S]
    float* __restrict__ proxyp)        // [512, E] per-block partial prob sums
{
    __shared__ float lds_p[4][EE];
    const int tid  = threadIdx.x;
    const int wave = tid >> 6;
    const int lane = tid & 63;         // = expert index for this lane

    const int t0 = blockIdx.x * 16 + wave * 4;
    const float* xr = x + (size_t)t0 * MM;

    float acc[4][4];
#pragma unroll
    for (int i = 0; i < 4; ++i)
#pragma unroll
        for (int j = 0; j < 4; ++j) acc[i][j] = 0.0f;

    for (int m = 0; m < MM; m += 4) {
        const float w0 = W[(m + 0) * EE + lane];
        const float w1 = W[(m + 1) * EE + lane];
        const float w2 = W[(m + 2) * EE + lane];
        const float w3 = W[(m + 3) * EE + lane];
#pragma unroll
        for (int i = 0; i < 4; ++i) {
            const float4 xv = *reinterpret_cast<const float4*>(xr + (size_t)i * MM + m);
            acc[i][0] = fmaf(xv.x, w0, acc[i][0]);
            acc[i][1] = fmaf(xv.y, w1, acc[i][1]);
            acc[i][2] = fmaf(xv.z, w2, acc[i][2]);
            acc[i][3] = fmaf(xv.w, w3, acc[i][3]);
        }
    }

    float myp = 0.0f;   // this lane's (expert's) softmax mass over its 4 tokens

#pragma unroll
    for (int i = 0; i < 4; ++i) {
        // combine stripes in fp64 (deterministic, argmax-safe vs fp32 ref)
        double logit = ((double)acc[i][0] + (double)acc[i][1]) +
                       ((double)acc[i][2] + (double)acc[i][3]);

        // argmax over lanes, first-index tie-break (np.argmax semantics)
        double v = logit;
        int idx = lane;
        for (int off = 32; off; off >>= 1) {
            double ov = __shfl_xor(v, off);
            int    oi = __shfl_xor(idx, off);
            if (ov > v || (ov == v && oi < idx)) { v = ov; idx = oi; }
        }

        float p  = __expf((float)(logit - v));
        float ps = p;
        for (int off = 32; off; off >>= 1) ps += __shfl_xor(ps, off);
        float inv = 1.0f / ps;          // softmax value at the argmax
        myp = fmaf(p, inv, myp);

        if (lane == 0) {
            expert_out[t0 + i] = idx;
            gate_out[t0 + i]   = inv;
        }
    }

    lds_p[wave][lane] = myp;
    __syncthreads();
    if (tid < EE)
        proxyp[(size_t)blockIdx.x * EE + tid] =
            (lds_p[0][tid] + lds_p[1][tid]) + (lds_p[2][tid] + lds_p[3][tid]);
}

// ---------------------------------------------------------------------------
// Kernel B: exclusive cumsum over sequence per (g,e) via ballot scan.
// One wave per (g,e): 256 waves -> 64 blocks.
// ---------------------------------------------------------------------------
__global__ __launch_bounds__(256) void scan_kernel(
    const int* __restrict__ expert,   // [G*S]
    int* __restrict__ pos,            // [G*S]
    int* __restrict__ count)          // [G*E]
{
    const int wid  = (int)((blockIdx.x * blockDim.x + threadIdx.x) >> 6);
    const int lane = threadIdx.x & 63;
    const int g = wid >> 6;
    const int e = wid & 63;
    const int* ex = expert + g * SS;

    int running = 0;
    for (int s0 = 0; s0 < SS; s0 += 64) {
        const int myex = ex[s0 + lane];
        const unsigned long long m = __ballot(myex == e);
        if (myex == e) {
            const int r = __popcll(m & ((1ull << lane) - 1ull));
            pos[g * SS + s0 + lane] = running + r;
        }
        running += __popcll(m);
    }
    if (lane == 0) count[g * EE + e] = running;
}

// ---------------------------------------------------------------------------
// Kernel C: paint — blocks [0, TOKENS) stream the full combine_tensor and
// dispatch_mask with nontemporal float4 stores (zeros + single hot slot per
// token). Block TOKENS computes the aux loss (reduces proxy partials+counts).
// ---------------------------------------------------------------------------
__global__ __launch_bounds__(256) void paint_kernel(
    const int*   __restrict__ expert,
    const float* __restrict__ gate,
    const int*   __restrict__ pos,
    const float* __restrict__ proxyp,  // [512, E]
    const int*   __restrict__ count,   // [G*E]
    floatx4* __restrict__ out,         // combine as float4; dispatch at +N4
    float*  __restrict__ out_aux)
{
    if (blockIdx.x == TOKENS) {
        // aux loss: thread i -> (g,e)
        __shared__ float red[4];
        const int i = threadIdx.x;
        const int g = i >> 6, e = i & 63;
        float s = 0.0f;
        for (int j = 0; j < BLK_PER_G; ++j)
            s += proxyp[(size_t)(g * BLK_PER_G + j) * EE + e];
        const float denom = (float)SS * (1.0f + 1e-6f);
        float term = (s / denom) * ((float)count[i] / denom);
        for (int off = 32; off; off >>= 1) term += __shfl_xor(term, off);
        if ((i & 63) == 0) red[i >> 6] = term;
        __syncthreads();
        if (i == 0) {
            float tot = (red[0] + red[1]) + (red[2] + red[3]);
            *out_aux = tot / (float)(GG * EE) * ((float)(EE * EE) * 0.01f);
        }
        return;
    }

    const int t   = blockIdx.x;        // token 0..8191
    const int e_t = expert[t];
    const int p   = pos[t];
    const float gv = gate[t];
    const bool kept = (p < CAP);
    const int hot_idx = e_t * ROWQ + (p >> 2);

    const size_t base = (size_t)t * (EE * ROWQ);
    const size_t N4   = (size_t)TOKENS * (EE * ROWQ);

    const floatx4 z = (floatx4)(0.0f);
#pragma unroll
    for (int k = 0; k < (EE * ROWQ) / 256; ++k) {
        const int idx = threadIdx.x + k * 256;
        floatx4 vc = z, vd = z;
        if (kept && idx == hot_idx) {
            vc[p & 3] = gv;
            vd[p & 3] = 1.0f;
        }
        __builtin_nontemporal_store(vc, &out[base + idx]);
        __builtin_nontemporal_store(vd, &out[N4 + base + idx]);
    }
}

// ---------------------------------------------------------------------------
extern "C" void kernel_launch(void* const* d_in, const int* in_sizes, int n_in,
                              void* d_out, int out_size, void* d_ws, size_t ws_size,
                              hipStream_t stream) {
    const float* x = (const float*)d_in[0];
    const float* W = (const float*)d_in[1];
    float* out = (float*)d_out;

    const size_t N = (size_t)TOKENS * EE * CAP;   // elements per output tensor

    // workspace layout (each slot written before read; no zeroing needed)
    float* proxyp = (float*)d_ws;                       // 512*64 floats
    int*   expert = (int*)(proxyp + (TOKENS / 16) * EE);
    float* gate   = (float*)(expert + TOKENS);
    int*   pos    = (int*)(gate + TOKENS);
    int*   count  = (int*)(pos + TOKENS);

    gating_kernel<<<TOKENS / 16, 256, 0, stream>>>(x, W, expert, gate, proxyp);
    scan_kernel<<<(GG * EE) / 4, 256, 0, stream>>>(expert, pos, count);
    paint_kernel<<<TOKENS + 1, 256, 0, stream>>>(expert, gate, pos, proxyp, count,
                                                 (floatx4*)out, out + 2 * N);
}